// Round 3
// baseline (135.619 us; speedup 1.0000x reference)
//
#include <hip/hip_runtime.h>
#include <math.h>

#define K 3
#define K2 9
#define BB 4
#define C 64
#define H 128
#define W 128
#define O 64
#define HW (H*W)
#define Ho 128
#define Wo 128
#define TILE 64        // pixels per block (along w)

typedef _Float16 half4v __attribute__((ext_vector_type(4)));
typedef _Float16 half8v __attribute__((ext_vector_type(8)));
typedef float float4v __attribute__((ext_vector_type(4)));

__device__ __forceinline__ half8v bcast8(_Float16 w) {
    half8v v = {w, w, w, w, w, w, w, w};
    return v;
}

#define MFMA16(a, b, c) __builtin_amdgcn_mfma_f32_16x16x32_f16((a), (b), (c), 0, 0, 0)
#define SB() __builtin_amdgcn_sched_barrier(0)

// ---------------------------------------------------------------------------
// prep_all: blocks [0, BB*H) build xh (NCHW fp32 -> NHWC fp16, LDS transpose);
// blocks [BB*H, BB*H+144) pack MFMA B-fragments, TAP-MAJOR K: k = tap*64 + ch.
//  wB : [tap*2+s][q=o-tile(4)][lane(64)][jj(8)], ch = s*32+(lane>>4)*8+jj
//  wAB: [tap*2+s][jt=n-tile(2)][lane(64)][jj(8)], n = jt*16+(lane&15) in 0..26
// ---------------------------------------------------------------------------
__global__ __launch_bounds__(256) void prep_all(
    const float* __restrict__ x,
    const float* __restrict__ weight,
    const float* __restrict__ offset_w,
    const float* __restrict__ mod_w,
    _Float16* __restrict__ xh,
    _Float16* __restrict__ wB,
    _Float16* __restrict__ wAB)
{
    int t = threadIdx.x;
    if (blockIdx.x < BB * H) {
        __shared__ _Float16 tile[W][68];     // x-pos x channel (pad 68)
        int by = blockIdx.x;
        int y = by % H, b = by / H;
        int xq = t & 31, cr = t >> 5;        // xq: float4 index, cr: 0..7
        #pragma unroll
        for (int g = 0; g < 8; g++) {
            int c = g * 8 + cr;
            float4v v = *(const float4v*)&x[(((size_t)b * C + c) * H + y) * W + xq * 4];
            tile[xq * 4 + 0][c] = (_Float16)v[0];
            tile[xq * 4 + 1][c] = (_Float16)v[1];
            tile[xq * 4 + 2][c] = (_Float16)v[2];
            tile[xq * 4 + 3][c] = (_Float16)v[3];
        }
        __syncthreads();
        int xp2 = t >> 1, hf = t & 1;        // each thread writes 32 ch = 64 B
        const _Float16* src = &tile[xp2][hf * 32];
        _Float16* dst = xh + (((size_t)b * H + y) * W + xp2) * 64 + hf * 32;
        #pragma unroll
        for (int i = 0; i < 8; i++)
            *(half4v*)(dst + i * 4) = *(const half4v*)(src + i * 4);
    } else {
        int i = (blockIdx.x - BB * H) * 256 + t;
        if (i < K2 * 2 * 4 * 64 * 8) {          // 36864
            int jj = i & 7;
            int lane = (i >> 3) & 63;
            int q4 = (i >> 9) & 3;
            int i2 = i >> 11;                    // tap*2 + s, [0,18)
            int tap = i2 >> 1, s = i2 & 1;
            int ch = s * 32 + ((lane >> 4) & 3) * 8 + jj;
            int o = q4 * 16 + (lane & 15);
            wB[i] = (_Float16)weight[(o * C + ch) * 9 + tap];
        }
        if (i < K2 * 2 * 2 * 64 * 8) {          // 18432
            int jj = i & 7;
            int lane = (i >> 3) & 63;
            int jt = (i >> 9) & 1;
            int i2 = i >> 10;                    // tap*2 + s
            int tap = i2 >> 1, s = i2 & 1;
            int ch = s * 32 + ((lane >> 4) & 3) * 8 + jj;
            int n = jt * 16 + (lane & 15);
            float wv = 0.f;
            if (n < 27)
                wv = (n < 18) ? offset_w[(n * C + ch) * 9 + tap]
                              : mod_w[((n - 18) * C + ch) * 9 + tap];
            wAB[i] = (_Float16)wv;
        }
    }
}

// ---------------------------------------------------------------------------
// fused_kernel: one block per (b,h,64px strip), 256 threads, 4 waves.
// REGISTER-RESIDENT A: each wave owns a 16-pixel strip (pw = q*16 + m16) and
// computes ALL 64 output channels (phase C) / all 27 aux channels (phase A).
// The MFMA A-fragment for (pw, k=s*32+quad*8+jj) is gathered directly by the
// owning lane into NAMED register scalars — no LDS A-tiles, no per-tap
// barriers. vs round 2: __launch_bounds__(256,4) lifts the VGPR cap from the
// default 8-wave/EU heuristic (~64 VGPR, which spilled the ~105-VGPR working
// set / defeated the prefetch) to 128 VGPR @ 4 waves/EU = our co-residency;
// sched_barrier(0) fences pin the LOAD(t+1) -> COMP(t) software pipeline so
// the scheduler cannot sink prefetch loads to their consumers.
// ---------------------------------------------------------------------------
__global__ __launch_bounds__(256, 4) void fused_kernel(
    const _Float16* __restrict__ xh,
    const _Float16* __restrict__ wB,
    const _Float16* __restrict__ wAB,
    const float* __restrict__ bias,
    const float* __restrict__ offset_b,
    const float* __restrict__ mod_b,
    float* __restrict__ out)
{
    __shared__ float s_buf[64 * 65];            // 16,640 B: s_res(27x65) / s_out(64x65)
    __shared__ unsigned int s_ai[K2 * TILE];    //  2,304 B (a00 | dx<<14 | dy<<15)
    __shared__ half4v s_wgt[K2 * TILE];         //  4,608 B (fp16 corner products)
    __shared__ float s_mm[TILE];                //    256 B
    float* s_res = s_buf;                       // phase A out [27][65]
    float* s_out = s_buf;                       // epilogue    [64][65]

    // XCD-aware swizzle: each XCD gets a contiguous 64-row h-band of one image.
    int blk = blockIdx.x;
    int xcd = blk & 7, idx = blk >> 3;
    int b  = xcd >> 1;
    int h  = ((xcd & 1) << 6) | (idx >> 1);
    int wt = idx & 1;
    int t  = threadIdx.x;
    int q  = t >> 6;                            // wave index
    int lane = t & 63;
    int m16 = lane & 15;
    int quad = (lane >> 4) & 3;
    int w0 = wt * TILE;
    int pw = q * 16 + m16;                      // this lane's owned pixel (in tile)

    const _Float16* xb = xh + (size_t)b * HW * 64;
    const _Float16* xbq = xb + quad * 8;        // lane's 16B channel segment base

    // ================= phase A: offset/mod conv (register A, ping-pong) =====
    float4v acc2[2];
    {
        float4v z = {0.f, 0.f, 0.f, 0.f};
        acc2[0] = z; acc2[1] = z;
    }

#define LOADA(tap, S) { \
    int ki = (tap) / 3, kj = (tap) % 3; \
    int y = h + ki - 1; \
    int xv = w0 + pw + kj - 1; \
    m##S = (_Float16)((y >= 0 && y < H && xv >= 0 && xv < W) ? 1.f : 0.f); \
    int yc = min(max(y, 0), H - 1); \
    int xc = min(max(xv, 0), W - 1); \
    const _Float16* src = xbq + ((size_t)(yc * W + xc)) * 64; \
    a##S##0 = *(const half8v*)(src); \
    a##S##1 = *(const half8v*)(src + 32); \
}
#define COMPA(tap, S) { \
    const _Float16* wp = wAB + (size_t)(tap) * 2048 + lane * 8; \
    half8v af0 = a##S##0 * bcast8(m##S); \
    acc2[0] = MFMA16(af0, *(const half8v*)(wp +    0), acc2[0]); \
    acc2[1] = MFMA16(af0, *(const half8v*)(wp +  512), acc2[1]); \
    half8v af1 = a##S##1 * bcast8(m##S); \
    acc2[0] = MFMA16(af1, *(const half8v*)(wp + 1024), acc2[0]); \
    acc2[1] = MFMA16(af1, *(const half8v*)(wp + 1536), acc2[1]); \
}

    {
        half8v aA0, aA1, aB0, aB1;
        _Float16 mA, mB;
        LOADA(0, A); SB(); LOADA(1, B); SB();
        COMPA(0, A); SB(); LOADA(2, A); SB();
        COMPA(1, B); SB(); LOADA(3, B); SB();
        COMPA(2, A); SB(); LOADA(4, A); SB();
        COMPA(3, B); SB(); LOADA(5, B); SB();
        COMPA(4, A); SB(); LOADA(6, A); SB();
        COMPA(5, B); SB(); LOADA(7, B); SB();
        COMPA(6, A); SB(); LOADA(8, A); SB();
        COMPA(7, B); SB();
        COMPA(8, A);
    }

    // C layout: col(n)=m16, row(px-in-wave-tile)=quad*4+reg; wave q owns px tile q
    #pragma unroll
    for (int jt = 0; jt < 2; jt++) {
        int n = jt * 16 + m16;
        if (n < 27) {
            #pragma unroll
            for (int r = 0; r < 4; r++)
                s_res[n * 65 + q * 16 + quad * 4 + r] = acc2[jt][r];
        }
    }
    __syncthreads();

    // ================= phase B: bilinear params + modmean =================
    #pragma unroll
    for (int ee = 0; ee < 3; ee++) {
        int e = t + ee * 256;
        if (e < K2 * TILE) {
            int k = e >> 6, p = e & 63;
            float offy = s_res[k * 65 + p] + offset_b[k];
            float offx = s_res[(9 + k) * 65 + p] + offset_b[9 + k];
            float sy = (float)(h + k / 3 - 1) + offy;
            float sx = (float)(w0 + p + k % 3 - 1) + offx;
            float fy = floorf(sy), fx = floorf(sx);
            int y0 = (int)fy, x0 = (int)fx;
            float wy1 = sy - fy, wx1 = sx - fx;
            int y0c = min(max(y0, 0), H - 1), y1c = min(max(y0 + 1, 0), H - 1);
            int x0c = min(max(x0, 0), W - 1), x1c = min(max(x0 + 1, 0), W - 1);
            s_ai[e] = (unsigned int)(y0c * W + x0c)
                    | ((unsigned int)(x1c - x0c) << 14)
                    | ((unsigned int)(y1c - y0c) << 15);
            float wg0 = (1.f - wy1) * ((y0 >= 0 && y0 < H) ? 1.f : 0.f);
            float wg1 = wy1 * ((y0 + 1 >= 0 && y0 + 1 < H) ? 1.f : 0.f);
            float wg2 = (1.f - wx1) * ((x0 >= 0 && x0 < W) ? 1.f : 0.f);
            float wg3 = wx1 * ((x0 + 1 >= 0 && x0 + 1 < W) ? 1.f : 0.f);
            half4v wp4;
            wp4[0] = (_Float16)(wg0 * wg2);   // (y0,x0)
            wp4[1] = (_Float16)(wg0 * wg3);   // (y0,x1)
            wp4[2] = (_Float16)(wg1 * wg2);   // (y1,x0)
            wp4[3] = (_Float16)(wg1 * wg3);   // (y1,x1)
            s_wgt[e] = wp4;
        }
    }
    if (t < TILE) {
        float sm = 0.f;
        #pragma unroll
        for (int m = 0; m < 9; m++) {
            float z = s_res[(18 + m) * 65 + t] + mod_b[m];
            sm += 1.f / (1.f + expf(-z));
        }
        s_mm[t] = sm * (1.f / 9.f);
    }
    __syncthreads();

    // ================= phase C: deform gather + main MFMA (register A) =====
    float4v acc[4];
    {
        float4v z = {0.f, 0.f, 0.f, 0.f};
        acc[0] = z; acc[1] = z; acc[2] = z; acc[3] = z;
    }

#define LOADC(tap, S) { \
    unsigned int ai = s_ai[(tap) * 64 + pw]; \
    wg##S = s_wgt[(tap) * 64 + pw]; \
    int a00 = ai & 0x3FFF; \
    int dxo = ((ai >> 14) & 1) << 6;          /* dx * 64 halves   */ \
    int dyo = ((ai >> 15) & 1) << 13;         /* dy * W*64 halves */ \
    const _Float16* base = xbq + (size_t)a00 * 64; \
    c##S##0 = *(const half8v*)(base); \
    c##S##1 = *(const half8v*)(base + dxo); \
    c##S##2 = *(const half8v*)(base + dyo); \
    c##S##3 = *(const half8v*)(base + dyo + dxo); \
    c##S##4 = *(const half8v*)(base + 32); \
    c##S##5 = *(const half8v*)(base + 32 + dxo); \
    c##S##6 = *(const half8v*)(base + 32 + dyo); \
    c##S##7 = *(const half8v*)(base + 32 + dyo + dxo); \
}
#define COMPC(tap, S) { \
    const _Float16* wp = wB + (size_t)(tap) * 4096 + lane * 8; \
    half8v af0 = c##S##0 * bcast8(wg##S[0]) + c##S##1 * bcast8(wg##S[1]) \
               + c##S##2 * bcast8(wg##S[2]) + c##S##3 * bcast8(wg##S[3]); \
    acc[0] = MFMA16(af0, *(const half8v*)(wp +    0), acc[0]); \
    acc[1] = MFMA16(af0, *(const half8v*)(wp +  512), acc[1]); \
    acc[2] = MFMA16(af0, *(const half8v*)(wp + 1024), acc[2]); \
    acc[3] = MFMA16(af0, *(const half8v*)(wp + 1536), acc[3]); \
    half8v af1 = c##S##4 * bcast8(wg##S[0]) + c##S##5 * bcast8(wg##S[1]) \
               + c##S##6 * bcast8(wg##S[2]) + c##S##7 * bcast8(wg##S[3]); \
    acc[0] = MFMA16(af1, *(const half8v*)(wp + 2048), acc[0]); \
    acc[1] = MFMA16(af1, *(const half8v*)(wp + 2560), acc[1]); \
    acc[2] = MFMA16(af1, *(const half8v*)(wp + 3072), acc[2]); \
    acc[3] = MFMA16(af1, *(const half8v*)(wp + 3584), acc[3]); \
}

    {
        half8v cA0, cA1, cA2, cA3, cA4, cA5, cA6, cA7;
        half8v cB0, cB1, cB2, cB3, cB4, cB5, cB6, cB7;
        half4v wgA, wgB;
        LOADC(0, A); SB(); LOADC(1, B); SB();
        COMPC(0, A); SB(); LOADC(2, A); SB();
        COMPC(1, B); SB(); LOADC(3, B); SB();
        COMPC(2, A); SB(); LOADC(4, A); SB();
        COMPC(3, B); SB(); LOADC(5, B); SB();
        COMPC(4, A); SB(); LOADC(6, A); SB();
        COMPC(5, B); SB(); LOADC(7, B); SB();
        COMPC(6, A); SB(); LOADC(8, A); SB();
        COMPC(7, B); SB();
        COMPC(8, A);
    }

    // ================= epilogue =================
    // acc[i]: col(m16) = o within o-tile i, row(quad*4+r) = px within wave tile
    #pragma unroll
    for (int i = 0; i < 4; i++) {
        #pragma unroll
        for (int r = 0; r < 4; r++)
            s_out[(i * 16 + m16) * 65 + q * 16 + quad * 4 + r] = acc[i][r];
    }
    __syncthreads();
    {
        float mm = s_mm[lane];
        #pragma unroll
        for (int jj = 0; jj < 16; jj++) {
            int o = q * 16 + jj;
            out[(((size_t)b * O + o) * Ho + h) * Wo + w0 + lane] =
                s_out[o * 65 + lane] * mm + bias[o];
        }
    }
}

extern "C" void kernel_launch(void* const* d_in, const int* in_sizes, int n_in,
                              void* d_out, int out_size, void* d_ws, size_t ws_size,
                              hipStream_t stream) {
    const float* x        = (const float*)d_in[0];
    const float* weight   = (const float*)d_in[1];
    const float* bias     = (const float*)d_in[2];
    const float* offset_w = (const float*)d_in[3];
    const float* offset_b = (const float*)d_in[4];
    const float* mod_w    = (const float*)d_in[5];
    const float* mod_b    = (const float*)d_in[6];
    float* out = (float*)d_out;

    // Workspace (halves): wB 36,864 | wAB 18,432 | xh 4,194,304 (byte 110,592, 16B-aligned)
    _Float16* wB  = (_Float16*)d_ws;
    _Float16* wAB = wB + 36864;
    _Float16* xh  = wAB + 18432;

    prep_all<<<BB * H + 144, 256, 0, stream>>>(
        x, weight, offset_w, mod_w, xh, wB, wAB);

    int nblk = BB * Ho * (Wo / TILE);   // 1024
    fused_kernel<<<nblk, 256, 0, stream>>>(
        xh, wB, wAB, bias, offset_b, mod_b, out);
}

// Round 4
// 107.139 us; speedup vs baseline: 1.2658x; 1.2658x over previous
//
#include <hip/hip_runtime.h>
#include <math.h>

#define K 3
#define K2 9
#define BB 4
#define C 64
#define H 128
#define W 128
#define O 64
#define HW (H*W)
#define Ho 128
#define Wo 128
#define TILE 64        // pixels per block (along w)

typedef _Float16 half4v __attribute__((ext_vector_type(4)));
typedef _Float16 half8v __attribute__((ext_vector_type(8)));
typedef float float4v __attribute__((ext_vector_type(4)));

__device__ __forceinline__ half8v bcast8(_Float16 w) {
    half8v v = {w, w, w, w, w, w, w, w};
    return v;
}

#define MFMA16(a, b, c) __builtin_amdgcn_mfma_f32_16x16x32_f16((a), (b), (c), 0, 0, 0)

// ---------------------------------------------------------------------------
// prep_all: blocks [0, BB*H) build xh (NCHW fp32 -> NHWC fp16, LDS transpose);
// blocks [BB*H, BB*H+144) pack MFMA B-fragments, TAP-MAJOR K: k = tap*64 + ch.
//  wB : [tap*2+s][q=o-tile(4)][lane(64)][jj(8)], ch = s*32+(lane>>4)*8+jj
//  wAB: [tap*2+s][jt=n-tile(2)][lane(64)][jj(8)], n = jt*16+(lane&15) in 0..26
// ---------------------------------------------------------------------------
__global__ __launch_bounds__(256) void prep_all(
    const float* __restrict__ x,
    const float* __restrict__ weight,
    const float* __restrict__ offset_w,
    const float* __restrict__ mod_w,
    _Float16* __restrict__ xh,
    _Float16* __restrict__ wB,
    _Float16* __restrict__ wAB)
{
    int t = threadIdx.x;
    if (blockIdx.x < BB * H) {
        __shared__ _Float16 tile[W][68];     // x-pos x channel (pad 68)
        int by = blockIdx.x;
        int y = by % H, b = by / H;
        int xq = t & 31, cr = t >> 5;        // xq: float4 index, cr: 0..7
        #pragma unroll
        for (int g = 0; g < 8; g++) {
            int c = g * 8 + cr;
            float4v v = *(const float4v*)&x[(((size_t)b * C + c) * H + y) * W + xq * 4];
            tile[xq * 4 + 0][c] = (_Float16)v[0];
            tile[xq * 4 + 1][c] = (_Float16)v[1];
            tile[xq * 4 + 2][c] = (_Float16)v[2];
            tile[xq * 4 + 3][c] = (_Float16)v[3];
        }
        __syncthreads();
        int xp2 = t >> 1, hf = t & 1;        // each thread writes 32 ch = 64 B
        const _Float16* src = &tile[xp2][hf * 32];
        _Float16* dst = xh + (((size_t)b * H + y) * W + xp2) * 64 + hf * 32;
        #pragma unroll
        for (int i = 0; i < 8; i++)
            *(half4v*)(dst + i * 4) = *(const half4v*)(src + i * 4);
    } else {
        int i = (blockIdx.x - BB * H) * 256 + t;
        if (i < K2 * 2 * 4 * 64 * 8) {          // 36864
            int jj = i & 7;
            int lane = (i >> 3) & 63;
            int q4 = (i >> 9) & 3;
            int i2 = i >> 11;                    // tap*2 + s, [0,18)
            int tap = i2 >> 1, s = i2 & 1;
            int ch = s * 32 + ((lane >> 4) & 3) * 8 + jj;
            int o = q4 * 16 + (lane & 15);
            wB[i] = (_Float16)weight[(o * C + ch) * 9 + tap];
        }
        if (i < K2 * 2 * 2 * 64 * 8) {          // 18432
            int jj = i & 7;
            int lane = (i >> 3) & 63;
            int jt = (i >> 9) & 1;
            int i2 = i >> 10;                    // tap*2 + s
            int tap = i2 >> 1, s = i2 & 1;
            int ch = s * 32 + ((lane >> 4) & 3) * 8 + jj;
            int n = jt * 16 + (lane & 15);
            float wv = 0.f;
            if (n < 27)
                wv = (n < 18) ? offset_w[(n * C + ch) * 9 + tap]
                              : mod_w[((n - 18) * C + ch) * 9 + tap];
            wAB[i] = (_Float16)wv;
        }
    }
}

// ---------------------------------------------------------------------------
// fused_kernel: one block per (b,h,64px strip), 256 threads, 4 waves.
// Round-0 cooperative structure (empirically fastest), improved:
//  * Phase A: the 9 taps only touch rows h-1..h+1 x 66px (25 KB). Staged ONCE
//    into LDS (zero-masked edges baked in), then 9 taps of pure ds_read+MFMA
//    with NO per-tap barriers (was: 9 gathers + 9 barriers).
//  * s_T / s_rows use linear rows + XOR swizzle (byte ^= (px&7)<<4) instead of
//    the TSTR=80 pad: A-frag ds_read_b128 conflicts 4-way -> ~2-way (free).
//  * LDS overlays by lifetime: {s_rows | s_T | s_out} share one 25.3 KB
//    region; s_res is separate (written right after phase-A MFMAs while other
//    waves may still read s_rows). Total 39.5 KB -> keeps 4 blocks/CU.
// Phase C: unchanged round-0 scheme (cooperative per-tap gather, ping-pong
// LDS, 1 barrier/tap) — accumulation order identical, absmax preserved.
// ---------------------------------------------------------------------------
__global__ __launch_bounds__(256) void fused_kernel(
    const _Float16* __restrict__ xh,
    const _Float16* __restrict__ wB,
    const _Float16* __restrict__ wAB,
    const float* __restrict__ bias,
    const float* __restrict__ offset_b,
    const float* __restrict__ mod_b,
    float* __restrict__ out)
{
    __shared__ __align__(16) unsigned char s_big[25344]; // s_rows[3][66][64]h | s_T[2][64][64]h | s_out[64][65]f
    __shared__ float s_res[27 * 65];            //  7,020 B (phase A out, separate: no barrier before write)
    __shared__ unsigned int s_ai[K2 * TILE];    //  2,304 B (a00 | dx<<14 | dy<<15)
    __shared__ half4v s_wgt[K2 * TILE];         //  4,608 B (fp16 corner products)
    __shared__ float s_mm[TILE];                //    256 B
    char* s_rowsB = (char*)s_big;               // phase A input rows (swizzled)
    char* s_TB    = (char*)s_big;               // phase C A-tiles (swizzled, dbuf)
    float* s_out  = (float*)s_big;              // epilogue [64][65]

    // XCD-aware swizzle: each XCD gets a contiguous 64-row h-band of one image.
    int blk = blockIdx.x;
    int xcd = blk & 7, idx = blk >> 3;
    int b  = xcd >> 1;
    int h  = ((xcd & 1) << 6) | (idx >> 1);
    int wt = idx & 1;
    int t  = threadIdx.x;
    int q  = t >> 6;                            // wave index
    int lane = t & 63;
    int m16 = lane & 15;
    int quad = (lane >> 4) & 3;
    int w0 = wt * TILE;
    int pw = q * 16 + m16;                      // wave-local pixel row for phase A
    int gpx0 = q * 16 + (lane >> 3);            // cooperative gather: pixel (pg=0)
    int seg  = lane & 7;                        // 16B channel segment

    const _Float16* xb = xh + (size_t)b * HW * 64;

    // ======== phase A stage: rows h-1..h+1 x 66 px, zero-masked, swizzled ===
    #pragma unroll
    for (int it = 0; it < 7; it++) {
        int e = t + it * 256;
        if (e < 3 * 66 * 8) {                   // 1584 16B chunks
            int sg = e & 7;
            int pr = e >> 3;                    // 0..197
            int yr = pr / 66;
            int px66 = pr - yr * 66;
            int y = h + yr - 1;
            int xv = w0 + px66 - 1;
            _Float16 mk = (_Float16)((y >= 0 && y < H && xv >= 0 && xv < W) ? 1.f : 0.f);
            int yc = min(max(y, 0), H - 1);
            int xc = min(max(xv, 0), W - 1);
            half8v v = *(const half8v*)(xb + ((size_t)(yc * W + xc)) * 64 + sg * 8);
            *(half8v*)(s_rowsB + (yr * 66 + px66) * 128 + ((sg * 16) ^ ((px66 & 7) << 4))) = v * bcast8(mk);
        }
    }
    __syncthreads();

    // ======== phase A compute: 9 taps, no barriers, ds_read + MFMA ==========
    float4v acc2[2];
    {
        float4v z = {0.f, 0.f, 0.f, 0.f};
        acc2[0] = z; acc2[1] = z;
    }

#define COMPA(tap) { \
    const int ki = (tap) / 3, kj = (tap) % 3; \
    int px66 = pw + kj; \
    const char* rbase = s_rowsB + (ki * 66 + px66) * 128; \
    int swz = (px66 & 7) << 4; \
    const _Float16* wp = wAB + (size_t)(tap) * 2048 + lane * 8; \
    half8v af0 = *(const half8v*)(rbase + ((quad * 16) ^ swz)); \
    acc2[0] = MFMA16(af0, *(const half8v*)(wp +    0), acc2[0]); \
    acc2[1] = MFMA16(af0, *(const half8v*)(wp +  512), acc2[1]); \
    half8v af1 = *(const half8v*)(rbase + ((64 + quad * 16) ^ swz)); \
    acc2[0] = MFMA16(af1, *(const half8v*)(wp + 1024), acc2[0]); \
    acc2[1] = MFMA16(af1, *(const half8v*)(wp + 1536), acc2[1]); \
}
    COMPA(0); COMPA(1); COMPA(2);
    COMPA(3); COMPA(4); COMPA(5);
    COMPA(6); COMPA(7); COMPA(8);

    // C layout: col(n)=m16, row(px-in-wave-tile)=quad*4+reg; wave q owns px tile q
    #pragma unroll
    for (int jt = 0; jt < 2; jt++) {
        int n = jt * 16 + m16;
        if (n < 27) {
            #pragma unroll
            for (int r = 0; r < 4; r++)
                s_res[n * 65 + q * 16 + quad * 4 + r] = acc2[jt][r];
        }
    }
    __syncthreads();

    // ================= phase B: bilinear params + modmean =================
    #pragma unroll
    for (int ee = 0; ee < 3; ee++) {
        int e = t + ee * 256;
        if (e < K2 * TILE) {
            int k = e >> 6, p = e & 63;
            float offy = s_res[k * 65 + p] + offset_b[k];
            float offx = s_res[(9 + k) * 65 + p] + offset_b[9 + k];
            float sy = (float)(h + k / 3 - 1) + offy;
            float sx = (float)(w0 + p + k % 3 - 1) + offx;
            float fy = floorf(sy), fx = floorf(sx);
            int y0 = (int)fy, x0 = (int)fx;
            float wy1 = sy - fy, wx1 = sx - fx;
            int y0c = min(max(y0, 0), H - 1), y1c = min(max(y0 + 1, 0), H - 1);
            int x0c = min(max(x0, 0), W - 1), x1c = min(max(x0 + 1, 0), W - 1);
            s_ai[e] = (unsigned int)(y0c * W + x0c)
                    | ((unsigned int)(x1c - x0c) << 14)
                    | ((unsigned int)(y1c - y0c) << 15);
            float wg0 = (1.f - wy1) * ((y0 >= 0 && y0 < H) ? 1.f : 0.f);
            float wg1 = wy1 * ((y0 + 1 >= 0 && y0 + 1 < H) ? 1.f : 0.f);
            float wg2 = (1.f - wx1) * ((x0 >= 0 && x0 < W) ? 1.f : 0.f);
            float wg3 = wx1 * ((x0 + 1 >= 0 && x0 + 1 < W) ? 1.f : 0.f);
            half4v wp4;
            wp4[0] = (_Float16)(wg0 * wg2);   // (y0,x0)
            wp4[1] = (_Float16)(wg0 * wg3);   // (y0,x1)
            wp4[2] = (_Float16)(wg1 * wg2);   // (y1,x0)
            wp4[3] = (_Float16)(wg1 * wg3);   // (y1,x1)
            s_wgt[e] = wp4;
        }
    }
    if (t < TILE) {
        float sm = 0.f;
        #pragma unroll
        for (int m = 0; m < 9; m++) {
            float z = s_res[(18 + m) * 65 + t] + mod_b[m];
            sm += 1.f / (1.f + expf(-z));
        }
        s_mm[t] = sm * (1.f / 9.f);
    }
    __syncthreads();

    // ================= phase C: deform gather + main MFMA (round-0 scheme) ==
    float4v acc[4];
    {
        float4v z = {0.f, 0.f, 0.f, 0.f};
        acc[0] = z; acc[1] = z; acc[2] = z; acc[3] = z;
    }

#define GATHER_LOAD(tapn, pg) { \
    int e = (tapn) * 64 + gpx0 + (pg) * 8; \
    unsigned int ai = s_ai[e]; \
    wgp##pg = s_wgt[e]; \
    int a00 = ai & 0x3FFF; \
    int dxo = ((ai >> 14) & 1) << 6;          /* dx * 64 halves   */ \
    int dyo = ((ai >> 15) & 1) << 13;         /* dy * W*64 halves */ \
    const _Float16* base = xb + (size_t)a00 * 64 + seg * 8; \
    r##pg##0 = *(const half8v*)(base); \
    r##pg##1 = *(const half8v*)(base + dxo); \
    r##pg##2 = *(const half8v*)(base + dyo); \
    r##pg##3 = *(const half8v*)(base + dyo + dxo); \
}
#define GATHER_STORE(buf, pg) { \
    int ppx = gpx0 + (pg) * 8; \
    half8v v = r##pg##0 * bcast8(wgp##pg[0]) + r##pg##1 * bcast8(wgp##pg[1]) \
             + r##pg##2 * bcast8(wgp##pg[2]) + r##pg##3 * bcast8(wgp##pg[3]); \
    *(half8v*)(s_TB + ((buf) * 64 + ppx) * 128 + ((seg * 16) ^ ((ppx & 7) << 4))) = v; \
}

    // prologue: gather tap 0 -> buf 0
    {
        half8v r00, r01, r02, r03, r10, r11, r12, r13;
        half4v wgp0, wgp1;
        GATHER_LOAD(0, 0); GATHER_LOAD(0, 1);
        GATHER_STORE(0, 0); GATHER_STORE(0, 1);
    }
    __syncthreads();

    #pragma unroll 1
    for (int tap = 0; tap < K2; tap++) {
        half8v r00, r01, r02, r03, r10, r11, r12, r13;
        half4v wgp0, wgp1;
        int buf = tap & 1;
        if (tap < 8) { GATHER_LOAD(tap + 1, 0); GATHER_LOAD(tap + 1, 1); }
        {
            const _Float16* wp = wB + (size_t)tap * 4096 + q * 512 + lane * 8;
            int swzT = (m16 & 7) << 4;
            const char* tb = s_TB + (buf * 64 + m16) * 128;
            #pragma unroll
            for (int s = 0; s < 2; s++) {
                half8v bf = *(const half8v*)(wp + s * 2048);
                #pragma unroll
                for (int i = 0; i < 4; i++) {
                    half8v af = *(const half8v*)(tb + i * 16 * 128 + ((s * 64 + quad * 16) ^ swzT));
                    acc[i] = MFMA16(af, bf, acc[i]);
                }
            }
        }
        if (tap < 8) { GATHER_STORE(buf ^ 1, 0); GATHER_STORE(buf ^ 1, 1); }
        __syncthreads();
    }

    // ================= epilogue =================
    // acc[i]: col(m16) = o within o-tile... o = q*16+m16; row = i*16+quad*4+r
    #pragma unroll
    for (int i = 0; i < 4; i++) {
        int o = q * 16 + m16;
        #pragma unroll
        for (int r = 0; r < 4; r++)
            s_out[o * 65 + i * 16 + quad * 4 + r] = acc[i][r];
    }
    __syncthreads();
    {
        float mm = s_mm[lane];
        #pragma unroll
        for (int jj = 0; jj < 16; jj++) {
            int o = q * 16 + jj;
            out[(((size_t)b * O + o) * Ho + h) * Wo + w0 + lane] =
                s_out[o * 65 + lane] * mm + bias[o];
        }
    }
}

extern "C" void kernel_launch(void* const* d_in, const int* in_sizes, int n_in,
                              void* d_out, int out_size, void* d_ws, size_t ws_size,
                              hipStream_t stream) {
    const float* x        = (const float*)d_in[0];
    const float* weight   = (const float*)d_in[1];
    const float* bias     = (const float*)d_in[2];
    const float* offset_w = (const float*)d_in[3];
    const float* offset_b = (const float*)d_in[4];
    const float* mod_w    = (const float*)d_in[5];
    const float* mod_b    = (const float*)d_in[6];
    float* out = (float*)d_out;

    // Workspace (halves): wB 36,864 | wAB 18,432 | xh 4,194,304 (byte 110,592, 16B-aligned)
    _Float16* wB  = (_Float16*)d_ws;
    _Float16* wAB = wB + 36864;
    _Float16* xh  = wAB + 18432;

    prep_all<<<BB * H + 144, 256, 0, stream>>>(
        x, weight, offset_w, mod_w, xh, wB, wAB);

    int nblk = BB * Ho * (Wo / TILE);   // 1024
    fused_kernel<<<nblk, 256, 0, stream>>>(
        xh, wB, wAB, bias, offset_b, mod_b, out);
}